// Round 1
// baseline (1889.028 us; speedup 1.0000x reference)
//
#include <hip/hip_runtime.h>
#include <cstdint>

#define BSZ 32
#define NVIS 1024      // h*w = num visual tokens
#define HID 256
#define TOKD 768
#define NCODE 2048
#define NPIX 32768     // BSZ*NVIS rows of flat

// ---------- helpers ----------
__device__ __forceinline__ unsigned long long pack_key(float d, int idx) {
  unsigned int b = __float_as_uint(d);
  b = (b & 0x80000000u) ? ~b : (b | 0x80000000u);  // monotonic float->uint
  return ((unsigned long long)b << 32) | (unsigned int)idx;
}

// ---------- tiny precompute kernels ----------
// cbnorm[n] = ||codebook[n]||^2
__global__ void code_norms(const float* __restrict__ cb, float* __restrict__ cbn) {
  int n = blockIdx.x, lane = threadIdx.x;  // 64 threads
  float a = 0.f;
#pragma unroll
  for (int i = 0; i < 12; ++i) { float v = cb[(long)n*TOKD + lane + 64*i]; a += v*v; }
#pragma unroll
  for (int off = 32; off; off >>= 1) a += __shfl_down(a, off);
  if (lane == 0) cbn[n] = a;
}

// M[c1*256+c2] = sum_t w_head[t,c1] * w_tail[c2,t]
__global__ void make_M(const float* __restrict__ wh, const float* __restrict__ wt,
                       float* __restrict__ Mm) {
  int c2 = blockIdx.x, c1 = threadIdx.x;
  float acc = 0.f;
  for (int t = 0; t < TOKD; ++t) acc += wh[t*HID + c1] * wt[c2*TOKD + t];
  Mm[c1*HID + c2] = acc;
}

// u[o*256+c1] = sum_t w_head[t,c1] * w_gate[o,768+t]
__global__ void make_u(const float* __restrict__ wh, const float* __restrict__ wg,
                       float* __restrict__ uv) {
  int o = blockIdx.x, c1 = threadIdx.x;
  float acc = 0.f;
  for (int t = 0; t < TOKD; ++t) acc += wh[t*HID + c1] * wg[o*(2*TOKD) + TOKD + t];
  uv[o*HID + c1] = acc;
}

// gA[o*2048+n] = sum_t poscode[n,t] * w_gate[o,t]
__global__ void make_gA(const float* __restrict__ poscode, const float* __restrict__ wg,
                        float* __restrict__ gA) {
  __shared__ float r0s[256], r1s[256];
  int n = blockIdx.x, tid = threadIdx.x;
  float a0 = 0.f, a1 = 0.f;
#pragma unroll
  for (int i = 0; i < 3; ++i) {
    float v = poscode[(long)n*TOKD + tid + 256*i];
    a0 += v * wg[tid + 256*i];
    a1 += v * wg[2*TOKD + tid + 256*i];
  }
  r0s[tid] = a0; r1s[tid] = a1; __syncthreads();
  for (int s = 128; s > 0; s >>= 1) {
    if (tid < s) { r0s[tid] += r0s[tid+s]; r1s[tid] += r1s[tid+s]; }
    __syncthreads();
  }
  if (tid == 0) { gA[n] = r0s[0]; gA[NCODE + n] = r1s[0]; }
}

// ---------- generic NT GEMM: C[m,n] = sum_k A[m,k]*B[n,k] (+bias[n]) ----------
// BM=BN=128, BK=16, 256 threads, 8x8 per thread. All dims divide evenly.
template<bool BIAS>
__global__ __launch_bounds__(256)
void gemm_nt128(const float* __restrict__ A, int lda, long sA,
                const float* __restrict__ B, int ldb, long sB,
                float* __restrict__ C, int ldc, long sC,
                int K, const float* __restrict__ bias) {
  __shared__ float As[16][128];
  __shared__ float Bs[16][128];
  const int tid = threadIdx.x;
  const long z = blockIdx.z;
  A += z * sA + (long)blockIdx.x * 128 * lda;
  B += z * sB + (long)blockIdx.y * 128 * ldb;
  C += z * sC + (long)blockIdx.x * 128 * ldc + blockIdx.y * 128;
  const int tm = tid >> 4, tn = tid & 15;
  const int r0 = tid >> 1;          // row this thread stages (0..127)
  const int kq = (tid & 1) * 8;     // k-offset 0 or 8
  float acc[8][8] = {};
  for (int kt = 0; kt < K; kt += 16) {
    float4 av0 = *(const float4*)(A + (long)r0*lda + kt + kq);
    float4 av1 = *(const float4*)(A + (long)r0*lda + kt + kq + 4);
    float4 bv0 = *(const float4*)(B + (long)r0*ldb + kt + kq);
    float4 bv1 = *(const float4*)(B + (long)r0*ldb + kt + kq + 4);
    __syncthreads();
    As[kq+0][r0]=av0.x; As[kq+1][r0]=av0.y; As[kq+2][r0]=av0.z; As[kq+3][r0]=av0.w;
    As[kq+4][r0]=av1.x; As[kq+5][r0]=av1.y; As[kq+6][r0]=av1.z; As[kq+7][r0]=av1.w;
    Bs[kq+0][r0]=bv0.x; Bs[kq+1][r0]=bv0.y; Bs[kq+2][r0]=bv0.z; Bs[kq+3][r0]=bv0.w;
    Bs[kq+4][r0]=bv1.x; Bs[kq+5][r0]=bv1.y; Bs[kq+6][r0]=bv1.z; Bs[kq+7][r0]=bv1.w;
    __syncthreads();
#pragma unroll
    for (int k = 0; k < 16; ++k) {
      float4 a0 = *(const float4*)&As[k][tm*8];
      float4 a1 = *(const float4*)&As[k][tm*8+4];
      float4 b0 = *(const float4*)&Bs[k][tn*8];
      float4 b1 = *(const float4*)&Bs[k][tn*8+4];
      float aa[8] = {a0.x,a0.y,a0.z,a0.w,a1.x,a1.y,a1.z,a1.w};
      float bb[8] = {b0.x,b0.y,b0.z,b0.w,b1.x,b1.y,b1.z,b1.w};
#pragma unroll
      for (int i = 0; i < 8; ++i)
#pragma unroll
        for (int j = 0; j < 8; ++j) acc[i][j] += aa[i]*bb[j];
    }
  }
  float bv[8];
  if (BIAS) {
#pragma unroll
    for (int j = 0; j < 8; ++j) bv[j] = bias[blockIdx.y*128 + tn*8 + j];
  }
#pragma unroll
  for (int i = 0; i < 8; ++i) {
    float* Cp = C + (long)(tm*8+i)*ldc + tn*8;
    float4 o0, o1;
    o0.x = acc[i][0]; o0.y = acc[i][1]; o0.z = acc[i][2]; o0.w = acc[i][3];
    o1.x = acc[i][4]; o1.y = acc[i][5]; o1.z = acc[i][6]; o1.w = acc[i][7];
    if (BIAS) {
      o0.x += bv[0]; o0.y += bv[1]; o0.z += bv[2]; o0.w += bv[3];
      o1.x += bv[4]; o1.y += bv[5]; o1.z += bv[6]; o1.w += bv[7];
    }
    *(float4*)(Cp) = o0; *(float4*)(Cp+4) = o1;
  }
}

// ---------- VQ: fused dist-GEMM + argmin ----------
// grid (NPIX/128, 2); block handles 128 rows x 1024 codes (8 tiles of 128).
__global__ __launch_bounds__(256)
void vq_argmin(const float* __restrict__ flat, const float* __restrict__ cb,
               const float* __restrict__ cbn, unsigned long long* __restrict__ keys) {
  __shared__ float As[16][128];
  __shared__ float Bs[16][128];
  __shared__ unsigned long long red[128][16];
  const int tid = threadIdx.x;
  const int rbase = blockIdx.x * 128;
  const int cbase = blockIdx.y * 1024;
  const int tm = tid >> 4, tn = tid & 15;
  const int r0 = tid >> 1;
  const int kq = (tid & 1) * 8;
  float bestd[8]; int besti[8];
#pragma unroll
  for (int i = 0; i < 8; ++i) { bestd[i] = 3.4e38f; besti[i] = 0; }
  for (int ct = 0; ct < 8; ++ct) {
    const float* Bp = cb + (long)(cbase + ct*128) * TOKD;
    float acc[8][8] = {};
    for (int kt = 0; kt < TOKD; kt += 16) {
      float4 av0 = *(const float4*)(flat + (long)(rbase + r0)*TOKD + kt + kq);
      float4 av1 = *(const float4*)(flat + (long)(rbase + r0)*TOKD + kt + kq + 4);
      float4 bv0 = *(const float4*)(Bp + (long)r0*TOKD + kt + kq);
      float4 bv1 = *(const float4*)(Bp + (long)r0*TOKD + kt + kq + 4);
      __syncthreads();
      As[kq+0][r0]=av0.x; As[kq+1][r0]=av0.y; As[kq+2][r0]=av0.z; As[kq+3][r0]=av0.w;
      As[kq+4][r0]=av1.x; As[kq+5][r0]=av1.y; As[kq+6][r0]=av1.z; As[kq+7][r0]=av1.w;
      Bs[kq+0][r0]=bv0.x; Bs[kq+1][r0]=bv0.y; Bs[kq+2][r0]=bv0.z; Bs[kq+3][r0]=bv0.w;
      Bs[kq+4][r0]=bv1.x; Bs[kq+5][r0]=bv1.y; Bs[kq+6][r0]=bv1.z; Bs[kq+7][r0]=bv1.w;
      __syncthreads();
#pragma unroll
      for (int k = 0; k < 16; ++k) {
        float4 a0 = *(const float4*)&As[k][tm*8];
        float4 a1 = *(const float4*)&As[k][tm*8+4];
        float4 b0 = *(const float4*)&Bs[k][tn*8];
        float4 b1 = *(const float4*)&Bs[k][tn*8+4];
        float aa[8] = {a0.x,a0.y,a0.z,a0.w,a1.x,a1.y,a1.z,a1.w};
        float bb[8] = {b0.x,b0.y,b0.z,b0.w,b1.x,b1.y,b1.z,b1.w};
#pragma unroll
        for (int i = 0; i < 8; ++i)
#pragma unroll
          for (int j = 0; j < 8; ++j) acc[i][j] += aa[i]*bb[j];
      }
    }
    const float4 cn0 = *(const float4*)(cbn + cbase + ct*128 + tn*8);
    const float4 cn1 = *(const float4*)(cbn + cbase + ct*128 + tn*8 + 4);
    float cnv[8] = {cn0.x,cn0.y,cn0.z,cn0.w,cn1.x,cn1.y,cn1.z,cn1.w};
#pragma unroll
    for (int j = 0; j < 8; ++j) {       // j outer: c ascends -> first-min ties
      int c = cbase + ct*128 + tn*8 + j;
#pragma unroll
      for (int i = 0; i < 8; ++i) {
        float d = cnv[j] - 2.0f * acc[i][j];
        if (d < bestd[i]) { bestd[i] = d; besti[i] = c; }
      }
    }
  }
#pragma unroll
  for (int i = 0; i < 8; ++i) red[tm*8+i][tn] = pack_key(bestd[i], besti[i]);
  __syncthreads();
  if (tid < 128) {
    unsigned long long k = red[tid][0];
#pragma unroll
    for (int t = 1; t < 16; ++t) { unsigned long long v = red[tid][t]; k = (v < k) ? v : k; }
    atomicMin(&keys[rbase + tid], k);
  }
}

__global__ void unpack_idx(const unsigned long long* __restrict__ keys,
                           int* __restrict__ idxv, float* __restrict__ outIdx) {
  int r = blockIdx.x * 256 + threadIdx.x;
  unsigned long long u = keys[r];
  int id = (int)(unsigned int)(u & 0xFFFFFFFFull);
  idxv[r] = id;
  outIdx[r] = (float)id;
}

// ---------- fused gate + tail output ----------
// block: 32 pixels x 256 out-channels; out[p,b,c] = s0*tailcode[idx,c] + s1*(src[p,b,:]@M)[c]
__global__ __launch_bounds__(256)
void fuse_out(const float* __restrict__ src, const int* __restrict__ idxv,
              const float* __restrict__ gA, const float* __restrict__ uvec,
              const float* __restrict__ Mm, const float* __restrict__ tailcode,
              float* __restrict__ out) {
  __shared__ float ss[32][257];
  __shared__ float s0s[32];
  __shared__ int ids[32];
  const int tid = threadIdx.x;
  const int rb = blockIdx.x * 32;
  const int b = rb >> 10;
  const int p0 = rb & 1023;
#pragma unroll
  for (int q = 0; q < 32; ++q)
    ss[q][tid] = src[(long)(p0 + q) * (BSZ*HID) + b*HID + tid];
  if (tid < 32) ids[tid] = idxv[rb + tid];
  __syncthreads();
  {
    const int wv = tid >> 6, lane = tid & 63;
    for (int qq = 0; qq < 8; ++qq) {
      int q = wv*8 + qq;
      float a0 = 0.f, a1 = 0.f;
#pragma unroll
      for (int i = 0; i < 4; ++i) {
        float v = ss[q][lane + 64*i];
        a0 += v * uvec[lane + 64*i];
        a1 += v * uvec[HID + lane + 64*i];
      }
#pragma unroll
      for (int off = 32; off; off >>= 1) { a0 += __shfl_down(a0, off); a1 += __shfl_down(a1, off); }
      if (lane == 0) {
        int id = ids[q];
        float l0 = gA[id] + a0;
        float l1 = gA[NCODE + id] + a1;
        s0s[q] = 1.0f / (1.0f + expf(l1 - l0));   // softmax over 2
      }
    }
  }
  __syncthreads();
  const int qg = tid >> 5, cg = tid & 31;
  const int q0 = qg * 4, c0 = cg * 8;
  float acc[4][8] = {};
  for (int cp = 0; cp < HID; ++cp) {
    float4 m0 = *(const float4*)(Mm + cp*HID + c0);
    float4 m1 = *(const float4*)(Mm + cp*HID + c0 + 4);
    float mm[8] = {m0.x,m0.y,m0.z,m0.w,m1.x,m1.y,m1.z,m1.w};
#pragma unroll
    for (int i = 0; i < 4; ++i) {
      float sv = ss[q0+i][cp];
#pragma unroll
      for (int j = 0; j < 8; ++j) acc[i][j] += sv * mm[j];
    }
  }
#pragma unroll
  for (int i = 0; i < 4; ++i) {
    int q = q0 + i;
    int id = ids[q];
    float s0 = s0s[q], s1 = 1.0f - s0;
    const float* tc = tailcode + (long)id*HID + c0;
    float* op = out + (long)(p0+q)*(BSZ*HID) + b*HID + c0;
    float4 o0, o1;
    o0.x = s0*tc[0] + s1*acc[i][0]; o0.y = s0*tc[1] + s1*acc[i][1];
    o0.z = s0*tc[2] + s1*acc[i][2]; o0.w = s0*tc[3] + s1*acc[i][3];
    o1.x = s0*tc[4] + s1*acc[i][4]; o1.y = s0*tc[5] + s1*acc[i][5];
    o1.z = s0*tc[6] + s1*acc[i][6]; o1.w = s0*tc[7] + s1*acc[i][7];
    *(float4*)(op) = o0; *(float4*)(op+4) = o1;
  }
}

// ---------- launch ----------
extern "C" void kernel_launch(void* const* d_in, const int* in_sizes, int n_in,
                              void* d_out, int out_size, void* d_ws, size_t ws_size,
                              hipStream_t stream) {
  const float* src    = (const float*)d_in[0];
  const float* cb     = (const float*)d_in[1];
  const float* w_head = (const float*)d_in[2];
  const float* w_tail = (const float*)d_in[3];
  const float* w_pos  = (const float*)d_in[4];
  const float* b_pos  = (const float*)d_in[5];
  const float* w_gate = (const float*)d_in[6];
  float* out = (float*)d_out;

  char* wsp = (char*)d_ws;
  size_t off = 0;
  auto alloc = [&](size_t bytes) {
    off = (off + 255) & ~(size_t)255;
    void* p = wsp + off; off += bytes; return p;
  };
  float* xq       = (float*)alloc((size_t)BSZ*TOKD*NVIS*4);   // 100.7 MB
  float* poscode  = (float*)alloc((size_t)NCODE*TOKD*4);
  float* tailcode = (float*)alloc((size_t)NCODE*HID*4);
  float* cbn      = (float*)alloc((size_t)NCODE*4);
  float* gA       = (float*)alloc((size_t)2*NCODE*4);
  float* Mm       = (float*)alloc((size_t)HID*HID*4);
  float* uvec     = (float*)alloc((size_t)2*HID*4);
  unsigned long long* keys = (unsigned long long*)alloc((size_t)NPIX*8);
  int* idxv       = (int*)alloc((size_t)NPIX*4);
  (void)ws_size; (void)in_sizes; (void)n_in; (void)out_size;

  code_norms<<<NCODE, 64, 0, stream>>>(cb, cbn);
  make_M<<<HID, HID, 0, stream>>>(w_head, w_tail, Mm);
  make_u<<<2, HID, 0, stream>>>(w_head, w_gate, uvec);
  // poscode = cb @ w_pos^T + b_pos   (2048 x 768, K=768)
  gemm_nt128<true ><<<dim3(NCODE/128, TOKD/128, 1), 256, 0, stream>>>(
      cb, TOKD, 0, w_pos, TOKD, 0, poscode, TOKD, 0, TOKD, b_pos);
  make_gA<<<NCODE, 256, 0, stream>>>(poscode, w_gate, gA);
  // tailcode = poscode @ w_tail^T    (2048 x 256, K=768)
  gemm_nt128<false><<<dim3(NCODE/128, HID/128, 1), 256, 0, stream>>>(
      poscode, TOKD, 0, w_tail, TOKD, 0, tailcode, HID, 0, TOKD, nullptr);
  // xq[b] = w_head @ src[:,b,:]^T    (768 x 1024 per batch, K=256)
  gemm_nt128<false><<<dim3(TOKD/128, NVIS/128, BSZ), 256, 0, stream>>>(
      w_head, HID, 0, src, BSZ*HID, HID, xq, NVIS, (long)TOKD*NVIS, HID, nullptr);
  // VQ argmin
  hipMemsetAsync(keys, 0xFF, (size_t)NPIX*8, stream);
  vq_argmin<<<dim3(NPIX/128, 2), 256, 0, stream>>>(xq, cb, cbn, keys);
  unpack_idx<<<NPIX/256, 256, 0, stream>>>(keys, idxv, out + (size_t)NVIS*BSZ*HID);
  fuse_out<<<NPIX/32, 256, 0, stream>>>(src, idxv, gA, uvec, Mm, tailcode, out);
}

// Round 3
// 1005.519 us; speedup vs baseline: 1.8787x; 1.8787x over previous
//
#include <hip/hip_runtime.h>
#include <cstdint>

#define BSZ 32
#define NVIS 1024
#define HID 256
#define TOKD 768
#define NCODE 2048
#define NPIX 32768

typedef _Float16 half8 __attribute__((ext_vector_type(8)));
typedef unsigned short ushort8 __attribute__((ext_vector_type(8)));
using f32x4 = __attribute__((ext_vector_type(4))) float;

__device__ __forceinline__ f32x4 mfmaF16(half8 a, half8 b, f32x4 c) {
  return __builtin_amdgcn_mfma_f32_16x16x32_f16(a, b, c, 0, 0, 0);
}

__device__ __forceinline__ unsigned long long pack_key(float d, int idx) {
  unsigned int b = __float_as_uint(d);
  b = (b & 0x80000000u) ? ~b : (b | 0x80000000u);  // monotonic float->uint
  return ((unsigned long long)b << 32) | (unsigned int)idx;
}

__device__ __forceinline__ void split16(float v, unsigned short& h, unsigned short& l) {
  union { _Float16 f; unsigned short u; } a, b;
  a.f = (_Float16)v;
  float hf = (float)a.f;
  b.f = (_Float16)(v - hf);
  h = a.u; l = b.u;
}

// ---------------- small precompute kernels ----------------

__global__ void split_pair(const float* __restrict__ x, unsigned short* __restrict__ h,
                           unsigned short* __restrict__ l, int n) {
  int i = blockIdx.x * 256 + threadIdx.x;
  if (i >= n) return;
  unsigned short hs, ls;
  split16(x[i], hs, ls);
  h[i] = hs; l[i] = ls;
}

// cbn[n] = ||cb[n]||^2 (exact fp32)
__global__ void code_norms(const float* __restrict__ cb, float* __restrict__ cbn) {
  int n = blockIdx.x, lane = threadIdx.x;
  float a = 0.f;
#pragma unroll
  for (int i = 0; i < 12; ++i) { float v = cb[(long)n*TOKD + lane + 64*i]; a += v*v; }
#pragma unroll
  for (int off = 32; off; off >>= 1) a += __shfl_down(a, off);
  if (lane == 0) cbn[n] = a;
}

// M[c1*256+c2] = sum_t wh[t,c1]*wt[c2,t]
__global__ void make_M(const float* __restrict__ wh, const float* __restrict__ wt,
                       float* __restrict__ Mm) {
  int c2 = blockIdx.x, c1 = threadIdx.x;
  float acc = 0.f;
  for (int t = 0; t < TOKD; ++t) acc += wh[t*HID + c1] * wt[c2*TOKD + t];
  Mm[c1*HID + c2] = acc;
}

// u[o*256+c1] = sum_t wh[t,c1]*wg[o,768+t]
__global__ void make_u(const float* __restrict__ wh, const float* __restrict__ wg,
                       float* __restrict__ uv) {
  int o = blockIdx.x, c1 = threadIdx.x;
  float acc = 0.f;
  for (int t = 0; t < TOKD; ++t) acc += wh[t*HID + c1] * wg[o*(2*TOKD) + TOKD + t];
  uv[o*HID + c1] = acc;
}

// gA[o*2048+n] = sum_t poscode[n,t] * w_gate[o,t]   (verified round 0)
__global__ void make_gA(const float* __restrict__ poscode, const float* __restrict__ wg,
                        float* __restrict__ gA) {
  __shared__ float r0s[256], r1s[256];
  int n = blockIdx.x, tid = threadIdx.x;
  float a0 = 0.f, a1 = 0.f;
#pragma unroll
  for (int i = 0; i < 3; ++i) {
    float v = poscode[(long)n*TOKD + tid + 256*i];
    a0 += v * wg[tid + 256*i];
    a1 += v * wg[2*TOKD + tid + 256*i];
  }
  r0s[tid] = a0; r1s[tid] = a1; __syncthreads();
  for (int s = 128; s > 0; s >>= 1) {
    if (tid < s) { r0s[tid] += r0s[tid+s]; r1s[tid] += r1s[tid+s]; }
    __syncthreads();
  }
  if (tid == 0) { gA[n] = r0s[0]; gA[NCODE + n] = r1s[0]; }
}

// ---------- generic fp32 NT GEMM (verified round 0) ----------
template<bool BIAS>
__global__ __launch_bounds__(256)
void gemm_nt128(const float* __restrict__ A, int lda, long sA,
                const float* __restrict__ B, int ldb, long sB,
                float* __restrict__ C, int ldc, long sC,
                int K, const float* __restrict__ bias) {
  __shared__ float As[16][128];
  __shared__ float Bs[16][128];
  const int tid = threadIdx.x;
  const long z = blockIdx.z;
  A += z * sA + (long)blockIdx.x * 128 * lda;
  B += z * sB + (long)blockIdx.y * 128 * ldb;
  C += z * sC + (long)blockIdx.x * 128 * ldc + blockIdx.y * 128;
  const int tm = tid >> 4, tn = tid & 15;
  const int r0 = tid >> 1;
  const int kq = (tid & 1) * 8;
  float acc[8][8] = {};
  for (int kt = 0; kt < K; kt += 16) {
    float4 av0 = *(const float4*)(A + (long)r0*lda + kt + kq);
    float4 av1 = *(const float4*)(A + (long)r0*lda + kt + kq + 4);
    float4 bv0 = *(const float4*)(B + (long)r0*ldb + kt + kq);
    float4 bv1 = *(const float4*)(B + (long)r0*ldb + kt + kq + 4);
    __syncthreads();
    As[kq+0][r0]=av0.x; As[kq+1][r0]=av0.y; As[kq+2][r0]=av0.z; As[kq+3][r0]=av0.w;
    As[kq+4][r0]=av1.x; As[kq+5][r0]=av1.y; As[kq+6][r0]=av1.z; As[kq+7][r0]=av1.w;
    Bs[kq+0][r0]=bv0.x; Bs[kq+1][r0]=bv0.y; Bs[kq+2][r0]=bv0.z; Bs[kq+3][r0]=bv0.w;
    Bs[kq+4][r0]=bv1.x; Bs[kq+5][r0]=bv1.y; Bs[kq+6][r0]=bv1.z; Bs[kq+7][r0]=bv1.w;
    __syncthreads();
#pragma unroll
    for (int k = 0; k < 16; ++k) {
      float4 a0 = *(const float4*)&As[k][tm*8];
      float4 a1 = *(const float4*)&As[k][tm*8+4];
      float4 b0 = *(const float4*)&Bs[k][tn*8];
      float4 b1 = *(const float4*)&Bs[k][tn*8+4];
      float aa[8] = {a0.x,a0.y,a0.z,a0.w,a1.x,a1.y,a1.z,a1.w};
      float bb[8] = {b0.x,b0.y,b0.z,b0.w,b1.x,b1.y,b1.z,b1.w};
#pragma unroll
      for (int i = 0; i < 8; ++i)
#pragma unroll
        for (int j = 0; j < 8; ++j) acc[i][j] += aa[i]*bb[j];
    }
  }
  float bv[8];
  if (BIAS) {
#pragma unroll
    for (int j = 0; j < 8; ++j) bv[j] = bias[blockIdx.y*128 + tn*8 + j];
  }
#pragma unroll
  for (int i = 0; i < 8; ++i) {
    float* Cp = C + (long)(tm*8+i)*ldc + tn*8;
    float4 o0, o1;
    o0.x = acc[i][0]; o0.y = acc[i][1]; o0.z = acc[i][2]; o0.w = acc[i][3];
    o1.x = acc[i][4]; o1.y = acc[i][5]; o1.z = acc[i][6]; o1.w = acc[i][7];
    if (BIAS) {
      o0.x += bv[0]; o0.y += bv[1]; o0.z += bv[2]; o0.w += bv[3];
      o1.x += bv[4]; o1.y += bv[5]; o1.z += bv[6]; o1.w += bv[7];
    }
    *(float4*)(Cp) = o0; *(float4*)(Cp+4) = o1;
  }
}

// ---------------- head GEMM (MFMA fp16 3-term): xq[b,o,p] = sum_c W[o,c]*S[p,b,c] ----------------
// grid (6, 8, 32), 256 threads. A = w_head split (global_load_lds); B = src fp32, split in-kernel.
__global__ __launch_bounds__(256)
void head_mfma(const unsigned short* __restrict__ whh, const unsigned short* __restrict__ whl,
               const float* __restrict__ src,
               unsigned short* __restrict__ xqh, unsigned short* __restrict__ xql) {
  __shared__ unsigned short Ah[2][4096] __attribute__((aligned(16)));
  __shared__ unsigned short Al[2][4096] __attribute__((aligned(16)));
  __shared__ unsigned short Bh[2][4096] __attribute__((aligned(16)));
  __shared__ unsigned short Bl[2][4096] __attribute__((aligned(16)));
  const int tid = threadIdx.x, lane = tid & 63, w = tid >> 6;
  const int n = lane & 15, q = lane >> 4;
  const int rh = w & 1, ch = w >> 1;
  const int obase = blockIdx.x * 128, pbase = blockIdx.y * 128, b = blockIdx.z;

  auto stageA = [&](int kc, int buf) {
#pragma unroll
    for (int is = 0; is < 2; ++is) {
      int c = is*256 + tid;
      int t = c >> 6, qq = (c >> 4) & 3, nn = c & 15;
      long off = (long)(obase + t*16 + nn)*HID + kc*32 + qq*8;
      __builtin_amdgcn_global_load_lds(
          (__attribute__((address_space(1))) void*)(whh + off),
          (__attribute__((address_space(3))) void*)&Ah[buf][c*8], 16, 0, 0);
      __builtin_amdgcn_global_load_lds(
          (__attribute__((address_space(1))) void*)(whl + off),
          (__attribute__((address_space(3))) void*)&Al[buf][c*8], 16, 0, 0);
    }
  };
  auto stageB = [&](int kc, int buf) {
#pragma unroll
    for (int is = 0; is < 2; ++is) {
      int c = is*256 + tid;
      int t = c >> 6, qq = (c >> 4) & 3, nn = c & 15;
      const float* gp = src + ((long)(pbase + t*16 + nn)*BSZ + b)*HID + kc*32 + qq*8;
      float4 v0 = *(const float4*)gp;
      float4 v1 = *(const float4*)(gp + 4);
      float vv[8] = {v0.x, v0.y, v0.z, v0.w, v1.x, v1.y, v1.z, v1.w};
      ushort8 hv, lv;
#pragma unroll
      for (int j = 0; j < 8; ++j) {
        unsigned short hs, ls;
        split16(vv[j], hs, ls);
        hv[j] = hs; lv[j] = ls;
      }
      *(ushort8*)&Bh[buf][c*8] = hv;
      *(ushort8*)&Bl[buf][c*8] = lv;
    }
  };

  f32x4 acc[4][4];
#pragma unroll
  for (int i = 0; i < 4; ++i)
#pragma unroll
    for (int j = 0; j < 4; ++j) acc[i][j] = (f32x4){0.f, 0.f, 0.f, 0.f};

  stageA(0, 0); stageB(0, 0);
  __syncthreads();

  for (int kt = 0; kt < HID/32; ++kt) {
    const int buf = kt & 1;
    if (kt + 1 < HID/32) { stageA(kt + 1, buf ^ 1); stageB(kt + 1, buf ^ 1); }
    half8 af[4][2], bf[4][2];
#pragma unroll
    for (int rt = 0; rt < 4; ++rt) {
      int idx = ((rh*4 + rt)*64 + q*16 + n)*8;
      af[rt][0] = *(const half8*)&Ah[buf][idx];
      af[rt][1] = *(const half8*)&Al[buf][idx];
    }
#pragma unroll
    for (int ct = 0; ct < 4; ++ct) {
      int idx = ((ch*4 + ct)*64 + q*16 + n)*8;
      bf[ct][0] = *(const half8*)&Bh[buf][idx];
      bf[ct][1] = *(const half8*)&Bl[buf][idx];
    }
#pragma unroll
    for (int rt = 0; rt < 4; ++rt)
#pragma unroll
      for (int ct = 0; ct < 4; ++ct) {
        acc[rt][ct] = mfmaF16(af[rt][0], bf[ct][0], acc[rt][ct]);
        acc[rt][ct] = mfmaF16(af[rt][0], bf[ct][1], acc[rt][ct]);
        acc[rt][ct] = mfmaF16(af[rt][1], bf[ct][0], acc[rt][ct]);
      }
    __syncthreads();
  }

#pragma unroll
  for (int rt = 0; rt < 4; ++rt)
#pragma unroll
    for (int ct = 0; ct < 4; ++ct)
#pragma unroll
      for (int reg = 0; reg < 4; ++reg) {
        int o = obase + rh*64 + rt*16 + q*4 + reg;
        int p = pbase + ch*64 + ct*16 + n;
        unsigned short hs, ls;
        split16(acc[rt][ct][reg], hs, ls);
        long off = (long)b*(TOKD*NVIS) + (long)o*NVIS + p;
        xqh[off] = hs; xql[off] = ls;
      }
}

// ---------------- VQ: fused dist-GEMM (fp16 3-term MFMA) + argmin ----------------
// 4096 blocks x 256 thr. Block = 128 flat rows x 128 codes, K=768.
__global__ __launch_bounds__(256)
void vq_mfma(const unsigned short* __restrict__ xqh, const unsigned short* __restrict__ xql,
             const unsigned short* __restrict__ cbh, const unsigned short* __restrict__ cbl,
             const float* __restrict__ cbn, unsigned long long* __restrict__ keys) {
  __shared__ unsigned short Ah[2][4096] __attribute__((aligned(16)));
  __shared__ unsigned short Al[2][4096] __attribute__((aligned(16)));
  __shared__ unsigned short Bh[2][4096] __attribute__((aligned(16)));
  __shared__ unsigned short Bl[2][4096] __attribute__((aligned(16)));
  __shared__ float cbns[128];
  // swizzle: supertile of 8 row-blocks x 16 code-blocks for L2 locality
  const int bid = blockIdx.x;
  const int g = bid >> 7, i = bid & 127;
  const int rb = g*8 + (i & 7);
  const int cblk = i >> 3;
  const int rowbase = rb * 128, codebase = cblk * 128;
  const int tid = threadIdx.x, lane = tid & 63, w = tid >> 6;
  const int n = lane & 15, q = lane >> 4;
  const int rh = w & 1, ch = w >> 1;

  if (tid < 128) cbns[tid] = cbn[codebase + tid];

  auto stage = [&](int kc, int buf) {
#pragma unroll
    for (int is = 0; is < 2; ++is) {
      int c = is*256 + tid;
      int t = c >> 6, qq = (c >> 4) & 3, nn = c & 15;
      long aoff = (long)(rowbase + t*16 + nn)*TOKD + kc*32 + qq*8;
      long boff = (long)(codebase + t*16 + nn)*TOKD + kc*32 + qq*8;
      __builtin_amdgcn_global_load_lds(
          (__attribute__((address_space(1))) void*)(xqh + aoff),
          (__attribute__((address_space(3))) void*)&Ah[buf][c*8], 16, 0, 0);
      __builtin_amdgcn_global_load_lds(
          (__attribute__((address_space(1))) void*)(xql + aoff),
          (__attribute__((address_space(3))) void*)&Al[buf][c*8], 16, 0, 0);
      __builtin_amdgcn_global_load_lds(
          (__attribute__((address_space(1))) void*)(cbh + boff),
          (__attribute__((address_space(3))) void*)&Bh[buf][c*8], 16, 0, 0);
      __builtin_amdgcn_global_load_lds(
          (__attribute__((address_space(1))) void*)(cbl + boff),
          (__attribute__((address_space(3))) void*)&Bl[buf][c*8], 16, 0, 0);
    }
  };

  f32x4 acc[4][4];
#pragma unroll
  for (int a = 0; a < 4; ++a)
#pragma unroll
    for (int b = 0; b < 4; ++b) acc[a][b] = (f32x4){0.f, 0.f, 0.f, 0.f};

  stage(0, 0);
  __syncthreads();

  for (int kt = 0; kt < TOKD/32; ++kt) {
    const int buf = kt & 1;
    if (kt + 1 < TOKD/32) stage(kt + 1, buf ^ 1);
    half8 af[4][2], bf[4][2];
#pragma unroll
    for (int rt = 0; rt < 4; ++rt) {
      int idx = ((rh*4 + rt)*64 + q*16 + n)*8;
      af[rt][0] = *(const half8*)&Ah[buf][idx];
      af[rt][1] = *(const half8*)&Al[buf][idx];
    }
#pragma unroll
    for (int ct = 0; ct < 4; ++ct) {
      int idx = ((ch*4 + ct)*64 + q*16 + n)*8;
      bf[ct][0] = *(const half8*)&Bh[buf][idx];
      bf[ct][1] = *(const half8*)&Bl[buf][idx];
    }
#pragma unroll
    for (int rt = 0; rt < 4; ++rt)
#pragma unroll
      for (int ct = 0; ct < 4; ++ct) {
        acc[rt][ct] = mfmaF16(af[rt][0], bf[ct][0], acc[rt][ct]);
        acc[rt][ct] = mfmaF16(af[rt][0], bf[ct][1], acc[rt][ct]);
        acc[rt][ct] = mfmaF16(af[rt][1], bf[ct][0], acc[rt][ct]);
      }
    __syncthreads();
  }

  // fused argmin: lane holds d for row = rh*64+rt*16+q*4+reg, code = ch*64+ct*16+n
#pragma unroll
  for (int rt = 0; rt < 4; ++rt) {
#pragma unroll
    for (int reg = 0; reg < 4; ++reg) {
      float bd = 3.4e38f; int bi = 0;
#pragma unroll
      for (int ct = 0; ct < 4; ++ct) {
        float d = cbns[ch*64 + ct*16 + n] - 2.0f * acc[rt][ct][reg];
        int code = codebase + ch*64 + ct*16 + n;
        if (d < bd) { bd = d; bi = code; }
      }
      unsigned long long k = pack_key(bd, bi);
      unsigned long long v;
      v = __shfl_xor(k, 1); k = (v < k) ? v : k;
      v = __shfl_xor(k, 2); k = (v < k) ? v : k;
      v = __shfl_xor(k, 4); k = (v < k) ? v : k;
      v = __shfl_xor(k, 8); k = (v < k) ? v : k;
      if (n == 0) {
        int row = rowbase + rh*64 + rt*16 + q*4 + reg;
        atomicMin(&keys[row], k);
      }
    }
  }
}

__global__ void unpack_idx(const unsigned long long* __restrict__ keys,
                           int* __restrict__ idxv, float* __restrict__ outIdx) {
  int r = blockIdx.x * 256 + threadIdx.x;
  unsigned long long u = keys[r];
  int id = (int)(unsigned int)(u & 0xFFFFFFFFull);
  idxv[r] = id;
  outIdx[r] = (float)id;
}

// ---------------- fused gate + tail output (verified round 0) ----------------
__global__ __launch_bounds__(256)
void fuse_out(const float* __restrict__ src, const int* __restrict__ idxv,
              const float* __restrict__ gA, const float* __restrict__ uvec,
              const float* __restrict__ Mm, const float* __restrict__ tailcode,
              float* __restrict__ out) {
  __shared__ float ss[32][257];
  __shared__ float s0s[32];
  __shared__ int ids[32];
  const int tid = threadIdx.x;
  const int rb = blockIdx.x * 32;
  const int b = rb >> 10;
  const int p0 = rb & 1023;
#pragma unroll
  for (int qq = 0; qq < 32; ++qq)
    ss[qq][tid] = src[(long)(p0 + qq) * (BSZ*HID) + b*HID + tid];
  if (tid < 32) ids[tid] = idxv[rb + tid];
  __syncthreads();
  {
    const int wv = tid >> 6, lane = tid & 63;
    for (int qq = 0; qq < 8; ++qq) {
      int qp = wv*8 + qq;
      float a0 = 0.f, a1 = 0.f;
#pragma unroll
      for (int i = 0; i < 4; ++i) {
        float v = ss[qp][lane + 64*i];
        a0 += v * uvec[lane + 64*i];
        a1 += v * uvec[HID + lane + 64*i];
      }
#pragma unroll
      for (int off = 32; off; off >>= 1) { a0 += __shfl_down(a0, off); a1 += __shfl_down(a1, off); }
      if (lane == 0) {
        int id = ids[qp];
        float l0 = gA[id] + a0;
        float l1 = gA[NCODE + id] + a1;
        s0s[qp] = 1.0f / (1.0f + expf(l1 - l0));
      }
    }
  }
  __syncthreads();
  const int qg = tid >> 5, cg = tid & 31;
  const int q0 = qg * 4, c0 = cg * 8;
  float acc[4][8] = {};
  for (int cp = 0; cp < HID; ++cp) {
    float4 m0 = *(const float4*)(Mm + cp*HID + c0);
    float4 m1 = *(const float4*)(Mm + cp*HID + c0 + 4);
    float mm[8] = {m0.x,m0.y,m0.z,m0.w,m1.x,m1.y,m1.z,m1.w};
#pragma unroll
    for (int i = 0; i < 4; ++i) {
      float sv = ss[q0+i][cp];
#pragma unroll
      for (int j = 0; j < 8; ++j) acc[i][j] += sv * mm[j];
    }
  }
#pragma unroll
  for (int i = 0; i < 4; ++i) {
    int qp = q0 + i;
    int id = ids[qp];
    float s0 = s0s[qp], s1 = 1.0f - s0;
    const float* tc = tailcode + (long)id*HID + c0;
    float* op = out + (long)(p0+qp)*(BSZ*HID) + b*HID + c0;
    float4 o0, o1;
    o0.x = s0*tc[0] + s1*acc[i][0]; o0.y = s0*tc[1] + s1*acc[i][1];
    o0.z = s0*tc[2] + s1*acc[i][2]; o0.w = s0*tc[3] + s1*acc[i][3];
    o1.x = s0*tc[4] + s1*acc[i][4]; o1.y = s0*tc[5] + s1*acc[i][5];
    o1.z = s0*tc[6] + s1*acc[i][6]; o1.w = s0*tc[7] + s1*acc[i][7];
    *(float4*)(op) = o0; *(float4*)(op+4) = o1;
  }
}

// ---------------- launch ----------------
extern "C" void kernel_launch(void* const* d_in, const int* in_sizes, int n_in,
                              void* d_out, int out_size, void* d_ws, size_t ws_size,
                              hipStream_t stream) {
  const float* src    = (const float*)d_in[0];
  const float* cb     = (const float*)d_in[1];
  const float* w_head = (const float*)d_in[2];
  const float* w_tail = (const float*)d_in[3];
  const float* w_pos  = (const float*)d_in[4];
  const float* b_pos  = (const float*)d_in[5];
  const float* w_gate = (const float*)d_in[6];
  float* out = (float*)d_out;

  char* wsp = (char*)d_ws;
  size_t off = 0;
  auto alloc = [&](size_t bytes) {
    off = (off + 255) & ~(size_t)255;
    void* p = wsp + off; off += bytes; return p;
  };
  unsigned short* xqh = (unsigned short*)alloc((size_t)BSZ*TOKD*NVIS*2);  // 50.3 MB
  unsigned short* xql = (unsigned short*)alloc((size_t)BSZ*TOKD*NVIS*2);  // 50.3 MB
  unsigned short* cbh = (unsigned short*)alloc((size_t)NCODE*TOKD*2);
  unsigned short* cbl = (unsigned short*)alloc((size_t)NCODE*TOKD*2);
  unsigned short* whh = (unsigned short*)alloc((size_t)TOKD*HID*2);
  unsigned short* whl = (unsigned short*)alloc((size_t)TOKD*HID*2);
  float* cbn      = (float*)alloc((size_t)NCODE*4);
  float* poscode  = (float*)alloc((size_t)NCODE*TOKD*4);
  float* tailcode = (float*)alloc((size_t)NCODE*HID*4);
  float* gA       = (float*)alloc((size_t)2*NCODE*4);
  float* Mm       = (float*)alloc((size_t)HID*HID*4);
  float* uvec     = (float*)alloc((size_t)2*HID*4);
  unsigned long long* keys = (unsigned long long*)alloc((size_t)NPIX*8);
  int* idxv       = (int*)alloc((size_t)NPIX*4);
  (void)ws_size; (void)in_sizes; (void)n_in; (void)out_size;

  // input splits + norms
  split_pair<<<(NCODE*TOKD + 255)/256, 256, 0, stream>>>(cb, cbh, cbl, NCODE*TOKD);
  split_pair<<<(TOKD*HID + 255)/256, 256, 0, stream>>>(w_head, whh, whl, TOKD*HID);
  code_norms<<<NCODE, 64, 0, stream>>>(cb, cbn);

  // xq = conv_head(src), raw layout [b][o][p], fp16 hi/lo
  head_mfma<<<dim3(TOKD/128, NVIS/128, BSZ), 256, 0, stream>>>(whh, whl, src, xqh, xql);

  // VQ argmin over 2048 codes
  hipMemsetAsync(keys, 0xFF, (size_t)NPIX*8, stream);
  vq_mfma<<<4096, 256, 0, stream>>>(xqh, xql, cbh, cbl, cbn, keys);
  unpack_idx<<<NPIX/256, 256, 0, stream>>>(keys, idxv, out + (size_t)NVIS*BSZ*HID);

  // verified round-0 precompute chain
  gemm_nt128<true ><<<dim3(NCODE/128, TOKD/128, 1), 256, 0, stream>>>(
      cb, TOKD, 0, w_pos, TOKD, 0, poscode, TOKD, 0, TOKD, b_pos);
  make_gA<<<NCODE, 256, 0, stream>>>(poscode, w_gate, gA);
  gemm_nt128<false><<<dim3(NCODE/128, HID/128, 1), 256, 0, stream>>>(
      poscode, TOKD, 0, w_tail, TOKD, 0, tailcode, HID, 0, TOKD, nullptr);
  make_M<<<HID, HID, 0, stream>>>(w_head, w_tail, Mm);
  make_u<<<2, HID, 0, stream>>>(w_head, w_gate, uvec);

  fuse_out<<<NPIX/32, 256, 0, stream>>>(src, idxv, gA, uvec, Mm, tailcode, out);
}

// Round 4
// 877.200 us; speedup vs baseline: 2.1535x; 1.1463x over previous
//
#include <hip/hip_runtime.h>
#include <cstdint>

#define BSZ 32
#define NVIS 1024
#define HID 256
#define TOKD 768
#define NCODE 2048
#define NPIX 32768

typedef unsigned short u16;
typedef _Float16 half8 __attribute__((ext_vector_type(8)));
typedef unsigned short ushort8 __attribute__((ext_vector_type(8)));
using f32x4 = __attribute__((ext_vector_type(4))) float;

#define AS1 __attribute__((address_space(1)))
#define AS3 __attribute__((address_space(3)))

__device__ __forceinline__ f32x4 mfmaF16(half8 a, half8 b, f32x4 c) {
  return __builtin_amdgcn_mfma_f32_16x16x32_f16(a, b, c, 0, 0, 0);
}

__device__ __forceinline__ unsigned long long pack_key(float d, int idx) {
  unsigned int b = __float_as_uint(d);
  b = (b & 0x80000000u) ? ~b : (b | 0x80000000u);  // monotonic float->uint
  return ((unsigned long long)b << 32) | (unsigned int)idx;
}

__device__ __forceinline__ void split16(float v, u16& h, u16& l) {
  union { _Float16 f; u16 u; } a, b;
  a.f = (_Float16)v;
  float hf = (float)a.f;
  b.f = (_Float16)(v - hf);
  h = a.u; l = b.u;
}

// ================= prep1: all weights-only precompute, one launch =================
// regions (256 threads each):
//  [0,6144)    split cb -> cbh/cbl
//  [6144,6912) split w_head -> whh/whl
//  [6912,7424) code norms (4 codes per block, wave each)
//  [7424,7680) make_M
//  [7680,7682) make_u
//  [7682,8450) make_Gt: Gt[tp*256+c] = sum_t wt[c,t]*wp[t,tp]
//  [8450,8453) g2[o*768+tp] = sum_t wp[t,tp]*wg[o*1536+t]
//  [8453,8454) ct0[c] = sum_t bp[t]*wt[c,t]
//  [8454,8455) cg[o] = sum_t bp[t]*wg[o*1536+t]
__global__ __launch_bounds__(256)
void prep1(const float* __restrict__ cb, const float* __restrict__ wh,
           const float* __restrict__ wt, const float* __restrict__ wp,
           const float* __restrict__ wg, const float* __restrict__ bp,
           u16* __restrict__ cbh, u16* __restrict__ cbl,
           u16* __restrict__ whh, u16* __restrict__ whl,
           float* __restrict__ cbn, float* __restrict__ Mm, float* __restrict__ uv,
           float* __restrict__ Gt, float* __restrict__ g2,
           float* __restrict__ ct0, float* __restrict__ cg) {
  const int bid = blockIdx.x, tid = threadIdx.x;
  if (bid < 6144) {                       // split cb
    int i = bid*256 + tid;
    u16 h, l; split16(cb[i], h, l);
    cbh[i] = h; cbl[i] = l;
  } else if (bid < 6912) {                // split w_head
    int i = (bid - 6144)*256 + tid;
    u16 h, l; split16(wh[i], h, l);
    whh[i] = h; whl[i] = l;
  } else if (bid < 7424) {                // code norms
    int n = (bid - 6912)*4 + (tid >> 6);
    int lane = tid & 63;
    float a = 0.f;
#pragma unroll
    for (int i = 0; i < 12; ++i) { float v = cb[(long)n*TOKD + lane + 64*i]; a += v*v; }
#pragma unroll
    for (int off = 32; off; off >>= 1) a += __shfl_down(a, off);
    if (lane == 0) cbn[n] = a;
  } else if (bid < 7680) {                // make_M
    int c2 = bid - 7424, c1 = tid;
    float acc = 0.f;
    for (int t = 0; t < TOKD; ++t) acc += wh[t*HID + c1] * wt[(long)c2*TOKD + t];
    Mm[c1*HID + c2] = acc;
  } else if (bid < 7682) {                // make_u
    int o = bid - 7680, c1 = tid;
    float acc = 0.f;
    for (int t = 0; t < TOKD; ++t) acc += wh[t*HID + c1] * wg[o*(2*TOKD) + TOKD + t];
    uv[o*HID + c1] = acc;
  } else if (bid < 8450) {                // make_Gt
    int rbid = bid - 7682;
    int c = rbid & 255, part = rbid >> 8;
    int tp = part*256 + tid;
    float acc = 0.f;
    for (int t = 0; t < TOKD; ++t) acc += wt[(long)c*TOKD + t] * wp[(long)t*TOKD + tp];
    Gt[(long)tp*HID + c] = acc;
  } else if (bid < 8453) {                // g2
    int tp = (bid - 8450)*256 + tid;
    float a0 = 0.f, a1 = 0.f;
    for (int t = 0; t < TOKD; ++t) {
      float wv = wp[(long)t*TOKD + tp];
      a0 += wv * wg[t];
      a1 += wv * wg[2*TOKD + t];
    }
    g2[tp] = a0; g2[TOKD + tp] = a1;
  } else if (bid < 8454) {                // ct0
    int c = tid;
    float a = 0.f;
    for (int t = 0; t < TOKD; ++t) a += bp[t] * wt[(long)c*TOKD + t];
    ct0[c] = a;
  } else {                                // cg
    int o = tid >> 6, lane = tid & 63;
    if (o < 2) {
      float a = 0.f;
      for (int t = lane; t < TOKD; t += 64) a += bp[t] * wg[o*(2*TOKD) + t];
#pragma unroll
      for (int off = 32; off; off >>= 1) a += __shfl_down(a, off);
      if (lane == 0) cg[o] = a;
    }
  }
}

// ================= prep2: tailcode + gA from shared cb tile =================
// 256 blocks x 8 codes. tailcode[n,c] = sum_tp cb[n,tp]*Gt[tp,c] + ct0[c];
// gA[o,n] = sum_tp cb[n,tp]*g2[o,tp] + cg[o]
__global__ __launch_bounds__(256)
void prep2(const float* __restrict__ cb, const float* __restrict__ Gt,
           const float* __restrict__ ct0, const float* __restrict__ g2,
           const float* __restrict__ cg, float* __restrict__ tc,
           float* __restrict__ gA) {
  __shared__ float cbs[8][TOKD];
  const int n0 = blockIdx.x * 8, tid = threadIdx.x;
  for (int i = tid; i < 8*TOKD; i += 256) cbs[i / TOKD][i % TOKD] = cb[(long)n0*TOKD + i];
  __syncthreads();
  float acc[8] = {};
  for (int t = 0; t < TOKD; ++t) {
    float gv = Gt[(long)t*HID + tid];
#pragma unroll
    for (int i = 0; i < 8; ++i) acc[i] += cbs[i][t] * gv;
  }
  float c0v = ct0[tid];
#pragma unroll
  for (int i = 0; i < 8; ++i) tc[(long)(n0+i)*HID + tid] = acc[i] + c0v;
  // gA: 32 threads per code
  {
    int i = tid >> 5, l32 = tid & 31;
    float a0 = 0.f, a1 = 0.f;
    for (int t = l32; t < TOKD; t += 32) {
      float cv = cbs[i][t];
      a0 += cv * g2[t];
      a1 += cv * g2[TOKD + t];
    }
#pragma unroll
    for (int off = 16; off; off >>= 1) { a0 += __shfl_down(a0, off); a1 += __shfl_down(a1, off); }
    if (l32 == 0) { gA[n0+i] = a0 + cg[0]; gA[NCODE + n0+i] = a1 + cg[1]; }
  }
}

// ================= head GEMM (MFMA fp16 3-term) with coalesced stores =================
// grid (6, 8, 32), 256 threads. xq[b,o,p] = sum_c w_head[o,c]*src[p,b,c]
__global__ __launch_bounds__(256)
void head_mfma(const u16* __restrict__ whh, const u16* __restrict__ whl,
               const float* __restrict__ src,
               u16* __restrict__ xqh, u16* __restrict__ xql) {
  __shared__ u16 SM[32768] __attribute__((aligned(16)));   // 64 KB
  u16* Ah = SM;            // [2][4096]
  u16* Al = SM + 8192;
  u16* Bh = SM + 16384;
  u16* Bl = SM + 24576;
  const int tid = threadIdx.x, lane = tid & 63, w = tid >> 6;
  const int n = lane & 15, q = lane >> 4;
  const int rh = w & 1, ch = w >> 1;
  const int obase = blockIdx.x * 128, pbase = blockIdx.y * 128, b = blockIdx.z;

  auto stageA = [&](int kc, int buf) {
#pragma unroll
    for (int is = 0; is < 2; ++is) {
      int c = is*256 + tid;
      int t = c >> 6, qq = (c >> 4) & 3, nn = c & 15;
      long off = (long)(obase + t*16 + nn)*HID + kc*32 + qq*8;
      __builtin_amdgcn_global_load_lds((AS1 void*)(whh + off),
          (AS3 void*)&Ah[buf*4096 + c*8], 16, 0, 0);
      __builtin_amdgcn_global_load_lds((AS1 void*)(whl + off),
          (AS3 void*)&Al[buf*4096 + c*8], 16, 0, 0);
    }
  };
  auto stageB = [&](int kc, int buf) {
#pragma unroll
    for (int is = 0; is < 2; ++is) {
      int c = is*256 + tid;
      int t = c >> 6, qq = (c >> 4) & 3, nn = c & 15;
      const float* gp = src + ((long)(pbase + t*16 + nn)*BSZ + b)*HID + kc*32 + qq*8;
      float4 v0 = *(const float4*)gp;
      float4 v1 = *(const float4*)(gp + 4);
      float vv[8] = {v0.x, v0.y, v0.z, v0.w, v1.x, v1.y, v1.z, v1.w};
      ushort8 hv, lv;
#pragma unroll
      for (int j = 0; j < 8; ++j) { u16 hs, ls; split16(vv[j], hs, ls); hv[j] = hs; lv[j] = ls; }
      *(ushort8*)&Bh[buf*4096 + c*8] = hv;
      *(ushort8*)&Bl[buf*4096 + c*8] = lv;
    }
  };

  f32x4 acc[4][4];
#pragma unroll
  for (int i = 0; i < 4; ++i)
#pragma unroll
    for (int j = 0; j < 4; ++j) acc[i][j] = (f32x4){0.f, 0.f, 0.f, 0.f};

  stageA(0, 0); stageB(0, 0);
  __syncthreads();

  for (int kt = 0; kt < HID/32; ++kt) {
    const int buf = kt & 1;
    if (kt + 1 < HID/32) { stageA(kt + 1, buf ^ 1); stageB(kt + 1, buf ^ 1); }
    half8 af[4][2], bf[4][2];
#pragma unroll
    for (int rt = 0; rt < 4; ++rt) {
      int idx = buf*4096 + ((rh*4 + rt)*64 + q*16 + n)*8;
      af[rt][0] = *(const half8*)&Ah[idx];
      af[rt][1] = *(const half8*)&Al[idx];
    }
#pragma unroll
    for (int ct = 0; ct < 4; ++ct) {
      int idx = buf*4096 + ((ch*4 + ct)*64 + q*16 + n)*8;
      bf[ct][0] = *(const half8*)&Bh[idx];
      bf[ct][1] = *(const half8*)&Bl[idx];
    }
#pragma unroll
    for (int rt = 0; rt < 4; ++rt)
#pragma unroll
      for (int ct = 0; ct < 4; ++ct) {
        acc[rt][ct] = mfmaF16(af[rt][0], bf[ct][0], acc[rt][ct]);
        acc[rt][ct] = mfmaF16(af[rt][0], bf[ct][1], acc[rt][ct]);
        acc[rt][ct] = mfmaF16(af[rt][1], bf[ct][0], acc[rt][ct]);
      }
    __syncthreads();
  }

  // transposed coalesced stores: two passes (hi, lo) through LDS [o][p] stride 136
#pragma unroll
  for (int pass = 0; pass < 2; ++pass) {
    u16* dst = pass ? xql : xqh;
#pragma unroll
    for (int rt = 0; rt < 4; ++rt)
#pragma unroll
      for (int ct = 0; ct < 4; ++ct)
#pragma unroll
        for (int reg = 0; reg < 4; ++reg) {
          u16 hs, ls; split16(acc[rt][ct][reg], hs, ls);
          int ol = rh*64 + rt*16 + q*4 + reg;
          int pl = ch*64 + ct*16 + n;
          SM[ol*136 + pl] = pass ? ls : hs;
        }
    __syncthreads();
#pragma unroll
    for (int s = 0; s < 8; ++s) {
      int cc = tid*8 + s;
      int o = cc >> 4, p8 = cc & 15;
      ushort8 v = *(const ushort8*)&SM[o*136 + p8*8];
      *(ushort8*)(dst + ((long)b*TOKD + obase + o)*NVIS + pbase + p8*8) = v;
    }
    __syncthreads();
  }
}

// ================= VQ: uniform K=2304 interleaved 3-term MFMA GEMM + argmin =================
// grid 4096 (bid = rb*16 + cblk), 256 threads, 128 rows x 128 codes, BK=32, LDS 33 KB.
__global__ __launch_bounds__(256, 4)
void vq_mfma(const u16* __restrict__ xqh, const u16* __restrict__ xql,
             const u16* __restrict__ cbh, const u16* __restrict__ cbl,
             const float* __restrict__ cbn, unsigned long long* __restrict__ keys) {
  __shared__ u16 Asm[2][4096] __attribute__((aligned(16)));
  __shared__ u16 Bsm[2][4096] __attribute__((aligned(16)));
  __shared__ float cbns[128];
  const int bid = blockIdx.x;
  const int rb = bid >> 4, cblk = bid & 15;
  const int rowbase = rb * 128, codebase = cblk * 128;
  const int tid = threadIdx.x, lane = tid & 63, w = tid >> 6;
  const int n = lane & 15, q = lane >> 4;
  const int rh = w & 1, ch = w >> 1;

  if (tid < 128) cbns[tid] = cbn[codebase + tid];

  // segments over kc in [0,72): [0,24) xh*eh | [24,48) xl*eh | [48,72) xh*el
  auto stage = [&](int kc, int buf) {
    int seg = (kc >= 48) ? 2 : (kc >= 24 ? 1 : 0);
    int kk = kc - seg*24;
    const u16* abase = (seg == 1) ? xql : xqh;
    const u16* bbase = (seg == 2) ? cbl : cbh;
#pragma unroll
    for (int is = 0; is < 2; ++is) {
      int c = is*256 + tid;
      int t = c >> 6, qq = (c >> 4) & 3, nn = c & 15;
      long aoff = (long)(rowbase + t*16 + nn)*TOKD + kk*32 + qq*8;
      long boff = (long)(codebase + t*16 + nn)*TOKD + kk*32 + qq*8;
      __builtin_amdgcn_global_load_lds((AS1 void*)(abase + aoff),
          (AS3 void*)&Asm[buf][c*8], 16, 0, 0);
      __builtin_amdgcn_global_load_lds((AS1 void*)(bbase + boff),
          (AS3 void*)&Bsm[buf][c*8], 16, 0, 0);
    }
  };

  f32x4 acc[4][4];
#pragma unroll
  for (int a = 0; a < 4; ++a)
#pragma unroll
    for (int b2 = 0; b2 < 4; ++b2) acc[a][b2] = (f32x4){0.f, 0.f, 0.f, 0.f};

  stage(0, 0);
  __syncthreads();

  for (int kc = 0; kc < 72; ++kc) {
    const int buf = kc & 1;
    if (kc + 1 < 72) stage(kc + 1, buf ^ 1);
    half8 af[4], bf[4];
#pragma unroll
    for (int rt = 0; rt < 4; ++rt)
      af[rt] = *(const half8*)&Asm[buf][((rh*4 + rt)*64 + q*16 + n)*8];
#pragma unroll
    for (int ct = 0; ct < 4; ++ct)
      bf[ct] = *(const half8*)&Bsm[buf][((ch*4 + ct)*64 + q*16 + n)*8];
#pragma unroll
    for (int rt = 0; rt < 4; ++rt)
#pragma unroll
      for (int ct = 0; ct < 4; ++ct)
        acc[rt][ct] = mfmaF16(af[rt], bf[ct], acc[rt][ct]);
    __syncthreads();
  }

  // fused argmin: lane holds d for row = rh*64+rt*16+q*4+reg, code = ch*64+ct*16+n
#pragma unroll
  for (int rt = 0; rt < 4; ++rt) {
#pragma unroll
    for (int reg = 0; reg < 4; ++reg) {
      float bd = 3.4e38f; int bi = 0;
#pragma unroll
      for (int ct = 0; ct < 4; ++ct) {
        float d = cbns[ch*64 + ct*16 + n] - 2.0f * acc[rt][ct][reg];
        int code = codebase + ch*64 + ct*16 + n;
        if (d < bd) { bd = d; bi = code; }
      }
      unsigned long long k = pack_key(bd, bi);
      unsigned long long v;
      v = __shfl_xor(k, 1); k = (v < k) ? v : k;
      v = __shfl_xor(k, 2); k = (v < k) ? v : k;
      v = __shfl_xor(k, 4); k = (v < k) ? v : k;
      v = __shfl_xor(k, 8); k = (v < k) ? v : k;
      if (n == 0) {
        int row = rowbase + rh*64 + rt*16 + q*4 + reg;
        atomicMin(&keys[row], k);
      }
    }
  }
}

__global__ void unpack_idx(const unsigned long long* __restrict__ keys,
                           int* __restrict__ idxv, float* __restrict__ outIdx) {
  int r = blockIdx.x * 256 + threadIdx.x;
  unsigned long long u = keys[r];
  int id = (int)(unsigned int)(u & 0xFFFFFFFFull);
  idxv[r] = id;
  outIdx[r] = (float)id;
}

// ================= fused gate + tail output (verified round 0/3) =================
__global__ __launch_bounds__(256)
void fuse_out(const float* __restrict__ src, const int* __restrict__ idxv,
              const float* __restrict__ gA, const float* __restrict__ uvec,
              const float* __restrict__ Mm, const float* __restrict__ tailcode,
              float* __restrict__ out) {
  __shared__ float ss[32][257];
  __shared__ float s0s[32];
  __shared__ int ids[32];
  const int tid = threadIdx.x;
  const int rb = blockIdx.x * 32;
  const int b = rb >> 10;
  const int p0 = rb & 1023;
#pragma unroll
  for (int qq = 0; qq < 32; ++qq)
    ss[qq][tid] = src[(long)(p0 + qq) * (BSZ*HID) + b*HID + tid];
  if (tid < 32) ids[tid] = idxv[rb + tid];
  __syncthreads();
  {
    const int wv = tid >> 6, lane = tid & 63;
    for (int qq = 0; qq < 8; ++qq) {
      int qp = wv*8 + qq;
      float a0 = 0.f, a1 = 0.f;
#pragma unroll
      for (int i = 0; i < 4; ++i) {
        float v = ss[qp][lane + 64*i];
        a0 += v * uvec[lane + 64*i];
        a1 += v * uvec[HID + lane + 64*i];
      }
#pragma unroll
      for (int off = 32; off; off >>= 1) { a0 += __shfl_down(a0, off); a1 += __shfl_down(a1, off); }
      if (lane == 0) {
        int id = ids[qp];
        float l0 = gA[id] + a0;
        float l1 = gA[NCODE + id] + a1;
        s0s[qp] = 1.0f / (1.0f + expf(l1 - l0));
      }
    }
  }
  __syncthreads();
  const int qg = tid >> 5, cg = tid & 31;
  const int q0 = qg * 4, c0 = cg * 8;
  float acc[4][8] = {};
  for (int cp = 0; cp < HID; ++cp) {
    float4 m0 = *(const float4*)(Mm + cp*HID + c0);
    float4 m1 = *(const float4*)(Mm + cp*HID + c0 + 4);
    float mm[8] = {m0.x,m0.y,m0.z,m0.w,m1.x,m1.y,m1.z,m1.w};
#pragma unroll
    for (int i = 0; i < 4; ++i) {
      float sv = ss[q0+i][cp];
#pragma unroll
      for (int j = 0; j < 8; ++j) acc[i][j] += sv * mm[j];
    }
  }
#pragma unroll
  for (int i = 0; i < 4; ++i) {
    int qp = q0 + i;
    int id = ids[qp];
    float s0 = s0s[qp], s1 = 1.0f - s0;
    const float* tc = tailcode + (long)id*HID + c0;
    float* op = out + (long)(p0+qp)*(BSZ*HID) + b*HID + c0;
    float4 o0, o1;
    o0.x = s0*tc[0] + s1*acc[i][0]; o0.y = s0*tc[1] + s1*acc[i][1];
    o0.z = s0*tc[2] + s1*acc[i][2]; o0.w = s0*tc[3] + s1*acc[i][3];
    o1.x = s0*tc[4] + s1*acc[i][4]; o1.y = s0*tc[5] + s1*acc[i][5];
    o1.z = s0*tc[6] + s1*acc[i][6]; o1.w = s0*tc[7] + s1*acc[i][7];
    *(float4*)(op) = o0; *(float4*)(op+4) = o1;
  }
}

// ================= launch =================
extern "C" void kernel_launch(void* const* d_in, const int* in_sizes, int n_in,
                              void* d_out, int out_size, void* d_ws, size_t ws_size,
                              hipStream_t stream) {
  const float* src    = (const float*)d_in[0];
  const float* cb     = (const float*)d_in[1];
  const float* w_head = (const float*)d_in[2];
  const float* w_tail = (const float*)d_in[3];
  const float* w_pos  = (const float*)d_in[4];
  const float* b_pos  = (const float*)d_in[5];
  const float* w_gate = (const float*)d_in[6];
  float* out = (float*)d_out;

  char* wsp = (char*)d_ws;
  size_t off = 0;
  auto alloc = [&](size_t bytes) {
    off = (off + 255) & ~(size_t)255;
    void* p = wsp + off; off += bytes; return p;
  };
  u16* xqh = (u16*)alloc((size_t)BSZ*TOKD*NVIS*2);  // 50.3 MB
  u16* xql = (u16*)alloc((size_t)BSZ*TOKD*NVIS*2);  // 50.3 MB
  u16* cbh = (u16*)alloc((size_t)NCODE*TOKD*2);
  u16* cbl = (u16*)alloc((size_t)NCODE*TOKD*2);
  u16* whh = (u16*)alloc((size_t)TOKD*HID*2);
  u16* whl = (u16*)alloc((size_t)TOKD*HID*2);
  float* cbn      = (float*)alloc((size_t)NCODE*4);
  float* Gt       = (float*)alloc((size_t)TOKD*HID*4);
  float* g2       = (float*)alloc((size_t)2*TOKD*4);
  float* ct0      = (float*)alloc((size_t)HID*4);
  float* cg       = (float*)alloc((size_t)2*4);
  float* tailcode = (float*)alloc((size_t)NCODE*HID*4);
  float* gA       = (float*)alloc((size_t)2*NCODE*4);
  float* Mm       = (float*)alloc((size_t)HID*HID*4);
  float* uvec     = (float*)alloc((size_t)2*HID*4);
  unsigned long long* keys = (unsigned long long*)alloc((size_t)NPIX*8);
  int* idxv       = (int*)alloc((size_t)NPIX*4);
  (void)ws_size; (void)in_sizes; (void)n_in; (void)out_size;

  prep1<<<8455, 256, 0, stream>>>(cb, w_head, w_tail, w_pos, w_gate, b_pos,
                                  cbh, cbl, whh, whl, cbn, Mm, uvec, Gt, g2, ct0, cg);
  prep2<<<NCODE/8, 256, 0, stream>>>(cb, Gt, ct0, g2, cg, tailcode, gA);

  head_mfma<<<dim3(TOKD/128, NVIS/128, BSZ), 256, 0, stream>>>(whh, whl, src, xqh, xql);

  hipMemsetAsync(keys, 0xFF, (size_t)NPIX*8, stream);
  vq_mfma<<<4096, 256, 0, stream>>>(xqh, xql, cbh, cbl, cbn, keys);
  unpack_idx<<<NPIX/256, 256, 0, stream>>>(keys, idxv, out + (size_t)NVIS*BSZ*HID);

  fuse_out<<<NPIX/32, 256, 0, stream>>>(src, idxv, gA, uvec, Mm, tailcode, out);
}